// Round 3
// baseline (468.332 us; speedup 1.0000x reference)
//
#include <hip/hip_runtime.h>
#include <cstdint>
#include <cstddef>

// ---------------- common ----------------
typedef __attribute__((ext_vector_type(8))) short short8;   // 8 x bf16 (4 VGPR)
typedef __attribute__((ext_vector_type(4))) short short4_;  // 4 x bf16 (2 VGPR)
typedef __attribute__((ext_vector_type(4))) float f32x4;    // MFMA C/D
typedef __attribute__((ext_vector_type(2))) unsigned int uint2_;

__device__ inline unsigned short bf16rne(float f) {
    uint32_t u = __builtin_bit_cast(uint32_t, f);
    u += 0x7fffu + ((u >> 16) & 1u);
    return (unsigned short)(u >> 16);
}

// async global->LDS, 16 B per lane. LDS dest = wave-uniform base + lane*16.
// CONTRACT (m104/m108): data lands at base + laneid*16 regardless of per-lane
// pointer; layout must be hole-free in lane order, ALL 64 lanes active.
#define GLDS(g, l)                                                              \
    __builtin_amdgcn_global_load_lds(                                           \
        (const __attribute__((address_space(1))) void*)(g),                     \
        (__attribute__((address_space(3))) void*)(l), 16, 0, 0)

// ---------------- fp32 -> bf16 convert ----------------
__global__ void cvt_kernel(const float* __restrict__ src,
                           unsigned short* __restrict__ dst, int n8) {
    int i = blockIdx.x * blockDim.x + threadIdx.x;
    if (i >= n8) return;
    const float4* s = (const float4*)src + (size_t)i * 2;
    float4 a = s[0], b = s[1];
    uint32_t w0 = bf16rne(a.x) | ((uint32_t)bf16rne(a.y) << 16);
    uint32_t w1 = bf16rne(a.z) | ((uint32_t)bf16rne(a.w) << 16);
    uint32_t w2 = bf16rne(b.x) | ((uint32_t)bf16rne(b.y) << 16);
    uint32_t w3 = bf16rne(b.z) | ((uint32_t)bf16rne(b.w) << 16);
    uint4 o; o.x = w0; o.y = w1; o.z = w2; o.w = w3;
    ((uint4*)dst)[i] = o;
}

// ---------------- QKV projection GEMM ----------------
// C[i][n] = sum_k X[i][k] * W[n][k] + b[n];  M = 128*gridDim.y, K=768, N=2304
// q,k stored bf16 as (b*12+h, 1024, 64) row-major.
// v stored TRANSPOSED: (b*12+h, 64, 1024)  [d-major, for attn PV A-frags]
__global__ __launch_bounds__(256) void qkv_gemm(
    const unsigned short* __restrict__ X, const unsigned short* __restrict__ W,
    const float* __restrict__ bqkv,
    unsigned short* __restrict__ qo, unsigned short* __restrict__ ko,
    unsigned short* __restrict__ vo)
{
    __shared__ unsigned short smem[16896];   // As[8192] Bs[8192] | epilogue Cs 128x132
    unsigned short* As = smem;
    unsigned short* Bs = smem + 8192;

    const int tid  = threadIdx.x;
    const int m0   = blockIdx.y * 128;
    const int n0   = blockIdx.x * 128;
    const int wid  = tid >> 6;
    const int lane = tid & 63;
    const int m16  = lane & 15;
    const int quad = lane >> 4;
    const int wm   = wid >> 1, wn = wid & 1;

    f32x4 acc[4][4];
    #pragma unroll
    for (int i = 0; i < 4; i++)
        #pragma unroll
        for (int j = 0; j < 4; j++) acc[i][j] = (f32x4){0.f, 0.f, 0.f, 0.f};

    for (int kt = 0; kt < 12; ++kt) {
        const int k0 = kt * 64;
        #pragma unroll
        for (int rd = 0; rd < 4; ++rd) {
            int id = rd * 256 + tid;
            int row = id >> 3, c = id & 7;
            GLDS(X + (size_t)(m0 + row) * 768 + k0 + c * 8, &As[id * 8]);
        }
        #pragma unroll
        for (int rd = 0; rd < 4; ++rd) {
            int id = rd * 256 + tid;
            int row = id >> 3, c = id & 7;
            GLDS(W + (size_t)(n0 + row) * 768 + k0 + c * 8, &Bs[id * 8]);
        }
        __syncthreads();
        #pragma unroll
        for (int ks = 0; ks < 2; ++ks) {
            short8 a[4], b[4];
            #pragma unroll
            for (int mb = 0; mb < 4; mb++)
                a[mb] = *(const short8*)&As[(wm * 64 + mb * 16 + m16) * 64 + ks * 32 + quad * 8];
            #pragma unroll
            for (int nb = 0; nb < 4; nb++)
                b[nb] = *(const short8*)&Bs[(wn * 64 + nb * 16 + m16) * 64 + ks * 32 + quad * 8];
            #pragma unroll
            for (int mb = 0; mb < 4; mb++)
                #pragma unroll
                for (int nb = 0; nb < 4; nb++)
                    acc[mb][nb] = __builtin_amdgcn_mfma_f32_16x16x32_bf16(
                        a[mb], b[nb], acc[mb][nb], 0, 0, 0);
        }
        __syncthreads();
    }

    float bias_n[4];
    #pragma unroll
    for (int nb = 0; nb < 4; nb++) bias_n[nb] = bqkv[n0 + wn * 64 + nb * 16 + m16];

    const int which = n0 / 768;
    const int hbase = (n0 % 768) / 64;
    const int bI  = m0 >> 10;      // batch index
    const int ns0 = m0 & 1023;

    if (which == 2) {
        // V: write transposed directly from acc (C-layout lane holds 4 consecutive
        // pos = quad*4+r for a fixed d-column) -> b64 stores into (bh,64,1024).
        #pragma unroll
        for (int mb = 0; mb < 4; ++mb)
            #pragma unroll
            for (int nb = 0; nb < 4; ++nb) {
                int n  = wn * 64 + nb * 16 + m16;
                int hh = hbase + (n >> 6);
                int d  = n & 63;
                int pos = ns0 + wm * 64 + mb * 16 + quad * 4;
                short4_ v4;
                #pragma unroll
                for (int r = 0; r < 4; ++r)
                    v4[r] = (short)bf16rne(acc[mb][nb][r] + bias_n[nb]);
                *(short4_*)(vo + ((size_t)(bI * 12 + hh) * 64 + d) * 1024 + pos) = v4;
            }
        return;
    }

    // Q/K: bias, bf16, repack via LDS (stride 132), row-major (bh,1024,64) stores
    #pragma unroll
    for (int mb = 0; mb < 4; mb++)
        #pragma unroll
        for (int nb = 0; nb < 4; nb++)
            #pragma unroll
            for (int r = 0; r < 4; r++) {
                float v = acc[mb][nb][r] + bias_n[nb];
                smem[(wm * 64 + mb * 16 + quad * 4 + r) * 132 + wn * 64 + nb * 16 + m16] =
                    bf16rne(v);
            }
    __syncthreads();

    unsigned short* outp = (which == 0) ? qo : ko;
    #pragma unroll
    for (int rd = 0; rd < 8; ++rd) {
        int id = rd * 256 + tid;
        int row = id >> 4, c = id & 15;
        short4_ lo = *(const short4_*)&smem[row * 132 + c * 8];
        short4_ hi = *(const short4_*)&smem[row * 132 + c * 8 + 4];
        short8 v8 = __builtin_shufflevector(lo, hi, 0, 1, 2, 3, 4, 5, 6, 7);
        int h  = hbase + (c >> 3);
        int dc = (c & 7) * 8;
        unsigned short* dst =
            outp + ((size_t)(bI * 12 + h) * 1024 + ns0 + row) * 64 + dc;
        *(short8*)dst = v8;
    }
}

// ---------------- flash attention (S^T formulation, double-buffered) ----------
// R8 = R7 resubmission (R7 bench was an infra failure; kernel audited clean:
// in-bounds staging/bias/Q/out, uniform barriers, GLDS wave-contract holds at
// 512 threads, launch_bounds satisfiable at measured 48 VGPR).
// 512-thread blocks, q-tile 128 (8 waves x 16 q-rows), same 32 KB LDS.
//   R6 counters: MfmaUtil 18.5 / VALUBusy 36 / HBM 10% / Occ 42% -> nothing
//   saturated = latency-bound at 20-wave ceiling (LDS capped 5 blocks/CU of
//   4 waves). 512-thread blocks keep LDS/block at 32 KB -> resident limit
//   becomes the WAVE limit: 4 blocks x 8 waves = 32 waves/CU (100%).
//   K/V staging + barriers per unit compute also halve.
// 1-D grid nbh*8, XCD-swizzled: f=(xcd | 8*(qt | 8*bhl)), bh=xcd*nbh8+bhl.
// All 8 q-tiles of one bh land on one XCD so K/V stay L2-resident per XCD.
// S^T = K·Q^T via 16x16x32 (C col = q-row, rows = pos) -> softmax is per-lane
// scalar state + 2 shuffles; P^T packed in registers via v_perm_b32 truncation
// (B-frag of 16x16x16bf16_1k) for O^T += V^T·P^T (no P LDS round-trip).
// T3 2-phase: GLDS for tile t+1 issue BEFORE compute on tile t; single
// vmcnt(0)+barrier per iter drains loads that had a full compute phase to land.
// Bias float4 loads software-pipelined one iter ahead.
// T13 defer-rescale THR=0: numerically identical, skips acc rescale when no
// row max grew.
//   Ks slot = pos*8 + (db ^ (pos&7)) -> b128 reads hit 8 dwords/bank (min)
//   Vs slot = pb*64 + d              -> b64  reads hit 4 dwords/bank (min)
__global__ __launch_bounds__(512, 8) void attn_kernel(
    const unsigned short* __restrict__ Q, const unsigned short* __restrict__ K,
    const unsigned short* __restrict__ Vt, const float* __restrict__ bias,
    const float* __restrict__ dvec, float* __restrict__ out, int nbh8)
{
    __shared__ unsigned short Ks[2][4096];   // 2 x 512 slots * 8 elems = 16 KB
    __shared__ unsigned short Vs[2][4096];   // 2 x 512 slots * 8 elems = 16 KB

    const int tid  = threadIdx.x;
    const int wid  = tid >> 6;               // 0..7
    const int lane = tid & 63;
    const int m16  = lane & 15;
    const int quad = lane >> 4;

    const int f    = blockIdx.x;
    const int xcd  = f & 7;
    const int r_   = f >> 3;
    const int qt   = r_ & 7;                 // 8 q-tiles of 128 rows
    const int bhl  = r_ >> 3;
    const int bh   = xcd * nbh8 + bhl;
    const int b = bh / 12, h = bh % 12;
    const int q0 = qt * 128;
    const int qrow = q0 + wid * 16 + m16;    // this lane's q row (column of S^T)

    const unsigned short* Qb = Q  + (size_t)bh * 65536;
    const unsigned short* Kb = K  + (size_t)bh * 65536;
    const unsigned short* Vb = Vt + (size_t)bh * 65536;
    const float* brow = bias + (size_t)qrow * 1024 + quad * 4;

    // kv-invariant staging source offsets (hole-free, all 512 lanes active;
    // one GLDS per thread per buffer: 512 slots x 8 elems = 64x64 tile)
    int k_src, v_src;
    {
        int pos = tid >> 3, dbs = tid & 7;
        int db = dbs ^ (pos & 7);             // un-swizzle: slot id holds this db
        k_src = pos * 64 + db * 8;
        int pb = tid >> 6, d = tid & 63;
        v_src = d * 1024 + pb * 8;
    }

    // Q fragments: B-operand of 16x16x32 (lane n=m16 holds dims quad*8..+8)
    short8 qf0 = *(const short8*)(Qb + (size_t)qrow * 64 + quad * 8);
    short8 qf1 = *(const short8*)(Qb + (size_t)qrow * 64 + 32 + quad * 8);

    f32x4 acc[4];
    #pragma unroll
    for (int nb = 0; nb < 4; nb++) acc[nb] = (f32x4){0.f, 0.f, 0.f, 0.f};
    float m_i = -3.0e38f, l_i = 0.f;

    // prologue: stage tile 0 + preload bias tile 0
    GLDS(Kb + k_src, &Ks[0][tid * 8]);
    GLDS(Vb + v_src, &Vs[0][tid * 8]);
    float4 bv[4];
    #pragma unroll
    for (int cb = 0; cb < 4; ++cb) bv[cb] = *(const float4*)(brow + cb * 16);
    __syncthreads();

    for (int kv = 0; kv < 16; ++kv) {
        const int cur = kv & 1;
        const int k0n = (kv + 1) * 64;

        // prefetch tile kv+1 (lands during this iter's compute; barrier drains)
        float4 bvn[4];
        if (kv < 15) {
            GLDS(Kb + (size_t)k0n * 64 + k_src, &Ks[cur ^ 1][tid * 8]);
            GLDS(Vb + (size_t)k0n + v_src, &Vs[cur ^ 1][tid * 8]);
            #pragma unroll
            for (int cb = 0; cb < 4; ++cb)
                bvn[cb] = *(const float4*)(brow + k0n + cb * 16);
        }

        // S^T = K·Q^T : sc[cb] rows = pos cb*16+quad*4+r, col = qrow(m16)
        f32x4 sc[4];
        #pragma unroll
        for (int cb = 0; cb < 4; ++cb) sc[cb] = (f32x4){0.f, 0.f, 0.f, 0.f};
        #pragma unroll
        for (int ks = 0; ks < 2; ++ks) {
            #pragma unroll
            for (int cb = 0; cb < 4; ++cb) {
                int pos = cb * 16 + m16;
                int slot = pos * 8 + ((ks * 4 + quad) ^ (m16 & 7));
                short8 a = *(const short8*)&Ks[cur][slot * 8];
                sc[cb] = __builtin_amdgcn_mfma_f32_16x16x32_bf16(
                    a, (ks == 0) ? qf0 : qf1, sc[cb], 0, 0, 0);
            }
        }

        // scale + bias (pipelined registers, zero-wait) + running max
        float mx = -3.0e38f;
        #pragma unroll
        for (int cb = 0; cb < 4; ++cb) {
            sc[cb][0] = sc[cb][0] * 0.125f + bv[cb].x;
            sc[cb][1] = sc[cb][1] * 0.125f + bv[cb].y;
            sc[cb][2] = sc[cb][2] * 0.125f + bv[cb].z;
            sc[cb][3] = sc[cb][3] * 0.125f + bv[cb].w;
            mx = fmaxf(mx, fmaxf(fmaxf(sc[cb][0], sc[cb][1]), fmaxf(sc[cb][2], sc[cb][3])));
        }
        mx = fmaxf(mx, __shfl_xor(mx, 16, 64));
        mx = fmaxf(mx, __shfl_xor(mx, 32, 64));

        // T13 defer-rescale (THR=0: exact — skipped only when per-row max
        // didn't grow, in which case the rescale would be exp(0)=1 anyway)
        if (!__all(mx <= m_i)) {
            float mnew = fmaxf(m_i, mx);
            float al = __expf(m_i - mnew);
            m_i = mnew;
            l_i *= al;
            #pragma unroll
            for (int nb = 0; nb < 4; nb++) {
                acc[nb][0] *= al; acc[nb][1] *= al;
                acc[nb][2] *= al; acc[nb][3] *= al;
            }
        }

        // exp + row-sum + pack P^T via v_perm_b32 truncation (2 elems/instr)
        float rs = 0.f;
        short4_ pf[4];
        #pragma unroll
        for (int cb = 0; cb < 4; ++cb) {
            float p0 = __expf(sc[cb][0] - m_i);
            float p1 = __expf(sc[cb][1] - m_i);
            float p2 = __expf(sc[cb][2] - m_i);
            float p3 = __expf(sc[cb][3] - m_i);
            rs += (p0 + p1) + (p2 + p3);
            uint2_ pd;
            pd[0] = __builtin_amdgcn_perm(__builtin_bit_cast(uint32_t, p1),
                                          __builtin_bit_cast(uint32_t, p0), 0x07060302u);
            pd[1] = __builtin_amdgcn_perm(__builtin_bit_cast(uint32_t, p3),
                                          __builtin_bit_cast(uint32_t, p2), 0x07060302u);
            pf[cb] = __builtin_bit_cast(short4_, pd);
        }
        rs += __shfl_xor(rs, 16, 64);
        rs += __shfl_xor(rs, 32, 64);
        l_i += rs;

        // O^T += V^T · P^T  (A = V^T frag from LDS, B = P^T in registers)
        #pragma unroll
        for (int ks = 0; ks < 4; ++ks) {
            #pragma unroll
            for (int nb = 0; nb < 4; ++nb) {
                int slot = (ks * 2 + (quad >> 1)) * 64 + nb * 16 + m16;
                short4_ av = *(const short4_*)&Vs[cur][slot * 8 + (quad & 1) * 4];
                acc[nb] = __builtin_amdgcn_mfma_f32_16x16x16bf16_1k(av, pf[ks], acc[nb], 0, 0, 0);
            }
        }

        // one barrier per iter: waits this iter's LDS reads AND drains the
        // prefetch (issued a full compute phase ago -> cheap)
        __syncthreads();
        if (kv < 15) {
            #pragma unroll
            for (int cb = 0; cb < 4; ++cb) bv[cb] = bvn[cb];
        }
    }

    // epilogue: out = d[qrow]/l * O ; O^T C-layout: lane holds d = nb*16+quad*4+r
    float scl = dvec[qrow] / l_i;
    #pragma unroll
    for (int nb = 0; nb < 4; ++nb) {
        float4 o;
        o.x = acc[nb][0] * scl; o.y = acc[nb][1] * scl;
        o.z = acc[nb][2] * scl; o.w = acc[nb][3] * scl;
        *(float4*)(out + ((size_t)b * 1024 + qrow) * 768 + h * 64 + nb * 16 + quad * 4) = o;
    }
}

// ---------------- launch ----------------
// xb (bf16 x, 25165824 B) lives in the upper half of d_out; every gemm that
// reads an xb region precedes (stream order) any attn write to that region.
// Workspace is layout-adaptive on ws_size (constant across calls => the same
// work every call):
//   full path  (ws >= 79,036,416 B): wb + full-size q/k/vT  -> 1 gemm + 1 attn
//   chunk path (ws >= 22,413,312 B): wb + 4-batch q/k/vT    -> 4x(gemm+attn)
extern "C" void kernel_launch(void* const* d_in, const int* in_sizes, int n_in,
                              void* d_out, int out_size, void* d_ws, size_t ws_size,
                              hipStream_t stream) {
    const float* x     = (const float*)d_in[0];   // (16,1024,768)
    const float* w     = (const float*)d_in[1];   // (2304,768)
    const float* bqkv  = (const float*)d_in[2];   // (2304,)
    const float* dvec  = (const float*)d_in[3];   // (1024,)
    const float* bbias = (const float*)d_in[4];   // (1024,1024)
    float* out = (float*)d_out;

    char* ws = (char*)d_ws;
    unsigned short* wb = (unsigned short*)ws;                        // 2304*768 bf16
    unsigned short* xb = (unsigned short*)((char*)d_out + 25165824); // 16*1024*768 bf16

    cvt_kernel<<<6144, 256, 0, stream>>>(x, xb, 1572864);            // all x -> bf16
    cvt_kernel<<<864, 256, 0, stream>>>(w, wb, 221184);              // w -> bf16

    const size_t NEED_FULL = 3538944ull + 3ull * 25165824ull;        // 79,036,416
    if (ws_size >= NEED_FULL) {
        unsigned short* qb = (unsigned short*)(ws + 3538944);        // 16*12*1024*64
        unsigned short* kb = qb + 12582912;
        unsigned short* vb = kb + 12582912;                          // V^T (bh,64,1024)
        qkv_gemm<<<dim3(18, 128), 256, 0, stream>>>(xb, wb, bqkv, qb, kb, vb);
        attn_kernel<<<1536, 512, 0, stream>>>(qb, kb, vb, bbias, dvec, out, 24);
    } else {
        unsigned short* qb = (unsigned short*)(ws + 3538944);        // 4*12*1024*64
        unsigned short* kb = qb + 3145728;
        unsigned short* vb = kb + 3145728;                           // V^T (bh,64,1024)
        for (int c = 0; c < 4; ++c) {
            const unsigned short* xc = xb + (size_t)c * 3145728;     // 4 batches
            qkv_gemm<<<dim3(18, 32), 256, 0, stream>>>(xc, wb, bqkv, qb, kb, vb);
            attn_kernel<<<384, 512, 0, stream>>>(
                qb, kb, vb, bbias, dvec, out + (size_t)c * 3145728, 6);
        }
    }
}

// Round 4
// 333.521 us; speedup vs baseline: 1.4042x; 1.4042x over previous
//
#include <hip/hip_runtime.h>
#include <cstdint>
#include <cstddef>

// ---------------- common ----------------
typedef __attribute__((ext_vector_type(8))) short short8;   // 8 x bf16 (4 VGPR)
typedef __attribute__((ext_vector_type(4))) short short4_;  // 4 x bf16 (2 VGPR)
typedef __attribute__((ext_vector_type(4))) float f32x4;    // MFMA C/D
typedef __attribute__((ext_vector_type(2))) unsigned int uint2_;

__device__ inline unsigned short bf16rne(float f) {
    uint32_t u = __builtin_bit_cast(uint32_t, f);
    u += 0x7fffu + ((u >> 16) & 1u);
    return (unsigned short)(u >> 16);
}

// async global->LDS, 16 B per lane. LDS dest = wave-uniform base + lane*16.
// CONTRACT (m104/m108): data lands at base + laneid*16 regardless of per-lane
// pointer; layout must be hole-free in lane order, ALL 64 lanes active.
#define GLDS(g, l)                                                              \
    __builtin_amdgcn_global_load_lds(                                           \
        (const __attribute__((address_space(1))) void*)(g),                     \
        (__attribute__((address_space(3))) void*)(l), 16, 0, 0)

// ---------------- fp32 -> bf16 convert ----------------
__global__ void cvt_kernel(const float* __restrict__ src,
                           unsigned short* __restrict__ dst, int n8) {
    int i = blockIdx.x * blockDim.x + threadIdx.x;
    if (i >= n8) return;
    const float4* s = (const float4*)src + (size_t)i * 2;
    float4 a = s[0], b = s[1];
    uint32_t w0 = bf16rne(a.x) | ((uint32_t)bf16rne(a.y) << 16);
    uint32_t w1 = bf16rne(a.z) | ((uint32_t)bf16rne(a.w) << 16);
    uint32_t w2 = bf16rne(b.x) | ((uint32_t)bf16rne(b.y) << 16);
    uint32_t w3 = bf16rne(b.z) | ((uint32_t)bf16rne(b.w) << 16);
    uint4 o; o.x = w0; o.y = w1; o.z = w2; o.w = w3;
    ((uint4*)dst)[i] = o;
}

// ---------------- QKV projection GEMM ----------------
// C[i][n] = sum_k X[i][k] * W[n][k] + b[n];  M = 128*gridDim.y, K=768, N=2304
// q,k stored bf16 as (b*12+h, 1024, 64) row-major.
// v stored TRANSPOSED: (b*12+h, 64, 1024)  [d-major, for attn PV A-frags]
__global__ __launch_bounds__(256) void qkv_gemm(
    const unsigned short* __restrict__ X, const unsigned short* __restrict__ W,
    const float* __restrict__ bqkv,
    unsigned short* __restrict__ qo, unsigned short* __restrict__ ko,
    unsigned short* __restrict__ vo)
{
    __shared__ unsigned short smem[16896];   // As[8192] Bs[8192] | epilogue Cs 128x132
    unsigned short* As = smem;
    unsigned short* Bs = smem + 8192;

    const int tid  = threadIdx.x;
    const int m0   = blockIdx.y * 128;
    const int n0   = blockIdx.x * 128;
    const int wid  = tid >> 6;
    const int lane = tid & 63;
    const int m16  = lane & 15;
    const int quad = lane >> 4;
    const int wm   = wid >> 1, wn = wid & 1;

    f32x4 acc[4][4];
    #pragma unroll
    for (int i = 0; i < 4; i++)
        #pragma unroll
        for (int j = 0; j < 4; j++) acc[i][j] = (f32x4){0.f, 0.f, 0.f, 0.f};

    for (int kt = 0; kt < 12; ++kt) {
        const int k0 = kt * 64;
        #pragma unroll
        for (int rd = 0; rd < 4; ++rd) {
            int id = rd * 256 + tid;
            int row = id >> 3, c = id & 7;
            GLDS(X + (size_t)(m0 + row) * 768 + k0 + c * 8, &As[id * 8]);
        }
        #pragma unroll
        for (int rd = 0; rd < 4; ++rd) {
            int id = rd * 256 + tid;
            int row = id >> 3, c = id & 7;
            GLDS(W + (size_t)(n0 + row) * 768 + k0 + c * 8, &Bs[id * 8]);
        }
        __syncthreads();
        #pragma unroll
        for (int ks = 0; ks < 2; ++ks) {
            short8 a[4], b[4];
            #pragma unroll
            for (int mb = 0; mb < 4; mb++)
                a[mb] = *(const short8*)&As[(wm * 64 + mb * 16 + m16) * 64 + ks * 32 + quad * 8];
            #pragma unroll
            for (int nb = 0; nb < 4; nb++)
                b[nb] = *(const short8*)&Bs[(wn * 64 + nb * 16 + m16) * 64 + ks * 32 + quad * 8];
            #pragma unroll
            for (int mb = 0; mb < 4; mb++)
                #pragma unroll
                for (int nb = 0; nb < 4; nb++)
                    acc[mb][nb] = __builtin_amdgcn_mfma_f32_16x16x32_bf16(
                        a[mb], b[nb], acc[mb][nb], 0, 0, 0);
        }
        __syncthreads();
    }

    float bias_n[4];
    #pragma unroll
    for (int nb = 0; nb < 4; nb++) bias_n[nb] = bqkv[n0 + wn * 64 + nb * 16 + m16];

    const int which = n0 / 768;
    const int hbase = (n0 % 768) / 64;
    const int bI  = m0 >> 10;      // batch index
    const int ns0 = m0 & 1023;

    if (which == 2) {
        // V: write transposed directly from acc (C-layout lane holds 4 consecutive
        // pos = quad*4+r for a fixed d-column) -> b64 stores into (bh,64,1024).
        #pragma unroll
        for (int mb = 0; mb < 4; ++mb)
            #pragma unroll
            for (int nb = 0; nb < 4; ++nb) {
                int n  = wn * 64 + nb * 16 + m16;
                int hh = hbase + (n >> 6);
                int d  = n & 63;
                int pos = ns0 + wm * 64 + mb * 16 + quad * 4;
                short4_ v4;
                #pragma unroll
                for (int r = 0; r < 4; ++r)
                    v4[r] = (short)bf16rne(acc[mb][nb][r] + bias_n[nb]);
                *(short4_*)(vo + ((size_t)(bI * 12 + hh) * 64 + d) * 1024 + pos) = v4;
            }
        return;
    }

    // Q/K: bias, bf16, repack via LDS (stride 132), row-major (bh,1024,64) stores
    #pragma unroll
    for (int mb = 0; mb < 4; mb++)
        #pragma unroll
        for (int nb = 0; nb < 4; nb++)
            #pragma unroll
            for (int r = 0; r < 4; r++) {
                float v = acc[mb][nb][r] + bias_n[nb];
                smem[(wm * 64 + mb * 16 + quad * 4 + r) * 132 + wn * 64 + nb * 16 + m16] =
                    bf16rne(v);
            }
    __syncthreads();

    unsigned short* outp = (which == 0) ? qo : ko;
    #pragma unroll
    for (int rd = 0; rd < 8; ++rd) {
        int id = rd * 256 + tid;
        int row = id >> 4, c = id & 15;
        short4_ lo = *(const short4_*)&smem[row * 132 + c * 8];
        short4_ hi = *(const short4_*)&smem[row * 132 + c * 8 + 4];
        short8 v8 = __builtin_shufflevector(lo, hi, 0, 1, 2, 3, 4, 5, 6, 7);
        int h  = hbase + (c >> 3);
        int dc = (c & 7) * 8;
        unsigned short* dst =
            outp + ((size_t)(bI * 12 + h) * 1024 + ns0 + row) * 64 + dc;
        *(short8*)dst = v8;
    }
}

// ---------------- flash attention (S^T formulation, double-buffered) ----------
// R9: fix R8's spill regression. R8 counters: VGPR_Count 32 (forced by
// launch_bounds(512,8) = 64-reg budget vs ~90-reg body) -> scratch spills
// (FETCH 540 MB / WRITE 341 MB, 41% HBM) dominated. Fix:
//   - __launch_bounds__(512, 4): 128-reg budget, spill impossible for this body
//   - bias pipeline halved 32->16 VGPR: S-MFMA C-operand initialized with
//     8*bias (exact: final *0.125 yields 0.125*KQ^T + bias), so bv[4] is
//     consumed at iter top and refilled by next-iter prefetch immediately.
//   Expected ~84-100 VGPR -> 5-6 waves/SIMD (20-24 waves/CU), >= R1 occupancy.
// Structure: 512-thread blocks, q-tile 128 (8 waves x 16 q-rows), 32 KB LDS
// (LDS per wave halved vs 256-thread blocks -> resident-wave ceiling lifted).
// 1-D grid nbh*8, XCD-swizzled: f=(xcd | 8*(qt | 8*bhl)), bh=xcd*nbh8+bhl.
// S^T = K·Q^T via 16x16x32 (C col = q-row, rows = pos) -> softmax is per-lane
// scalar state + 2 shuffles; P^T packed in registers via v_perm_b32 truncation
// (B-frag of 16x16x16bf16_1k) for O^T += V^T·P^T (no P LDS round-trip).
// T3 2-phase: GLDS for tile t+1 issue BEFORE compute on tile t; single
// vmcnt(0)+barrier per iter drains loads that had a full compute phase to land.
// T13 defer-rescale THR=0: numerically identical, skips acc rescale when no
// row max grew.
//   Ks slot = pos*8 + (db ^ (pos&7)) -> b128 reads hit 8 dwords/bank (min)
//   Vs slot = pb*64 + d              -> b64  reads hit 4 dwords/bank (min)
__global__ __launch_bounds__(512, 4) void attn_kernel(
    const unsigned short* __restrict__ Q, const unsigned short* __restrict__ K,
    const unsigned short* __restrict__ Vt, const float* __restrict__ bias,
    const float* __restrict__ dvec, float* __restrict__ out, int nbh8)
{
    __shared__ unsigned short Ks[2][4096];   // 2 x 512 slots * 8 elems = 16 KB
    __shared__ unsigned short Vs[2][4096];   // 2 x 512 slots * 8 elems = 16 KB

    const int tid  = threadIdx.x;
    const int wid  = tid >> 6;               // 0..7
    const int lane = tid & 63;
    const int m16  = lane & 15;
    const int quad = lane >> 4;

    const int f    = blockIdx.x;
    const int xcd  = f & 7;
    const int r_   = f >> 3;
    const int qt   = r_ & 7;                 // 8 q-tiles of 128 rows
    const int bhl  = r_ >> 3;
    const int bh   = xcd * nbh8 + bhl;
    const int b = bh / 12, h = bh % 12;
    const int q0 = qt * 128;
    const int qrow = q0 + wid * 16 + m16;    // this lane's q row (column of S^T)

    const unsigned short* Qb = Q  + (size_t)bh * 65536;
    const unsigned short* Kb = K  + (size_t)bh * 65536;
    const unsigned short* Vb = Vt + (size_t)bh * 65536;
    const float* brow = bias + (size_t)qrow * 1024 + quad * 4;

    // kv-invariant staging source offsets (hole-free, all 512 lanes active;
    // one GLDS per thread per buffer: 512 slots x 8 elems = 64x64 tile)
    int k_src, v_src;
    {
        int pos = tid >> 3, dbs = tid & 7;
        int db = dbs ^ (pos & 7);             // un-swizzle: slot id holds this db
        k_src = pos * 64 + db * 8;
        int pb = tid >> 6, d = tid & 63;
        v_src = d * 1024 + pb * 8;
    }

    // Q fragments: B-operand of 16x16x32 (lane n=m16 holds dims quad*8..+8)
    short8 qf0 = *(const short8*)(Qb + (size_t)qrow * 64 + quad * 8);
    short8 qf1 = *(const short8*)(Qb + (size_t)qrow * 64 + 32 + quad * 8);

    f32x4 acc[4];
    #pragma unroll
    for (int nb = 0; nb < 4; nb++) acc[nb] = (f32x4){0.f, 0.f, 0.f, 0.f};
    float m_i = -3.0e38f, l_i = 0.f;

    // prologue: stage tile 0 + preload bias tile 0
    GLDS(Kb + k_src, &Ks[0][tid * 8]);
    GLDS(Vb + v_src, &Vs[0][tid * 8]);
    float4 bv[4];
    #pragma unroll
    for (int cb = 0; cb < 4; ++cb) bv[cb] = *(const float4*)(brow + cb * 16);
    __syncthreads();

    for (int kv = 0; kv < 16; ++kv) {
        const int cur = kv & 1;
        const int k0n = (kv + 1) * 64;

        // S^T C-init = 8*bias (consumes bv; final *0.125 restores bias scale,
        // exact in fp32). Frees bv for the next-iter prefetch below.
        f32x4 sc[4];
        #pragma unroll
        for (int cb = 0; cb < 4; ++cb) {
            sc[cb][0] = bv[cb].x * 8.0f;
            sc[cb][1] = bv[cb].y * 8.0f;
            sc[cb][2] = bv[cb].z * 8.0f;
            sc[cb][3] = bv[cb].w * 8.0f;
        }

        // prefetch tile kv+1 (lands during this iter's compute; barrier drains)
        if (kv < 15) {
            GLDS(Kb + (size_t)k0n * 64 + k_src, &Ks[cur ^ 1][tid * 8]);
            GLDS(Vb + (size_t)k0n + v_src, &Vs[cur ^ 1][tid * 8]);
            #pragma unroll
            for (int cb = 0; cb < 4; ++cb)
                bv[cb] = *(const float4*)(brow + k0n + cb * 16);
        }

        // S^T = 8*bias + K·Q^T : sc[cb] rows = pos cb*16+quad*4+r, col = qrow
        #pragma unroll
        for (int ks = 0; ks < 2; ++ks) {
            #pragma unroll
            for (int cb = 0; cb < 4; ++cb) {
                int pos = cb * 16 + m16;
                int slot = pos * 8 + ((ks * 4 + quad) ^ (m16 & 7));
                short8 a = *(const short8*)&Ks[cur][slot * 8];
                sc[cb] = __builtin_amdgcn_mfma_f32_16x16x32_bf16(
                    a, (ks == 0) ? qf0 : qf1, sc[cb], 0, 0, 0);
            }
        }

        // *0.125 (finishes scale+bias) + running max
        float mx = -3.0e38f;
        #pragma unroll
        for (int cb = 0; cb < 4; ++cb) {
            sc[cb][0] *= 0.125f;
            sc[cb][1] *= 0.125f;
            sc[cb][2] *= 0.125f;
            sc[cb][3] *= 0.125f;
            mx = fmaxf(mx, fmaxf(fmaxf(sc[cb][0], sc[cb][1]), fmaxf(sc[cb][2], sc[cb][3])));
        }
        mx = fmaxf(mx, __shfl_xor(mx, 16, 64));
        mx = fmaxf(mx, __shfl_xor(mx, 32, 64));

        // T13 defer-rescale (THR=0: exact — skipped only when per-row max
        // didn't grow, in which case the rescale would be exp(0)=1 anyway)
        if (!__all(mx <= m_i)) {
            float mnew = fmaxf(m_i, mx);
            float al = __expf(m_i - mnew);
            m_i = mnew;
            l_i *= al;
            #pragma unroll
            for (int nb = 0; nb < 4; nb++) {
                acc[nb][0] *= al; acc[nb][1] *= al;
                acc[nb][2] *= al; acc[nb][3] *= al;
            }
        }

        // exp + row-sum + pack P^T via v_perm_b32 truncation (2 elems/instr)
        float rs = 0.f;
        short4_ pf[4];
        #pragma unroll
        for (int cb = 0; cb < 4; ++cb) {
            float p0 = __expf(sc[cb][0] - m_i);
            float p1 = __expf(sc[cb][1] - m_i);
            float p2 = __expf(sc[cb][2] - m_i);
            float p3 = __expf(sc[cb][3] - m_i);
            rs += (p0 + p1) + (p2 + p3);
            uint2_ pd;
            pd[0] = __builtin_amdgcn_perm(__builtin_bit_cast(uint32_t, p1),
                                          __builtin_bit_cast(uint32_t, p0), 0x07060302u);
            pd[1] = __builtin_amdgcn_perm(__builtin_bit_cast(uint32_t, p3),
                                          __builtin_bit_cast(uint32_t, p2), 0x07060302u);
            pf[cb] = __builtin_bit_cast(short4_, pd);
        }
        rs += __shfl_xor(rs, 16, 64);
        rs += __shfl_xor(rs, 32, 64);
        l_i += rs;

        // O^T += V^T · P^T  (A = V^T frag from LDS, B = P^T in registers)
        #pragma unroll
        for (int ks = 0; ks < 4; ++ks) {
            #pragma unroll
            for (int nb = 0; nb < 4; ++nb) {
                int slot = (ks * 2 + (quad >> 1)) * 64 + nb * 16 + m16;
                short4_ av = *(const short4_*)&Vs[cur][slot * 8 + (quad & 1) * 4];
                acc[nb] = __builtin_amdgcn_mfma_f32_16x16x16bf16_1k(av, pf[ks], acc[nb], 0, 0, 0);
            }
        }

        // one barrier per iter: waits this iter's LDS reads AND drains the
        // prefetch (issued a full compute phase ago -> cheap)
        __syncthreads();
    }

    // epilogue: out = d[qrow]/l * O ; O^T C-layout: lane holds d = nb*16+quad*4+r
    float scl = dvec[qrow] / l_i;
    #pragma unroll
    for (int nb = 0; nb < 4; ++nb) {
        float4 o;
        o.x = acc[nb][0] * scl; o.y = acc[nb][1] * scl;
        o.z = acc[nb][2] * scl; o.w = acc[nb][3] * scl;
        *(float4*)(out + ((size_t)b * 1024 + qrow) * 768 + h * 64 + nb * 16 + quad * 4) = o;
    }
}

// ---------------- launch ----------------
// xb (bf16 x, 25165824 B) lives in the upper half of d_out; every gemm that
// reads an xb region precedes (stream order) any attn write to that region.
// Workspace is layout-adaptive on ws_size (constant across calls => the same
// work every call):
//   full path  (ws >= 79,036,416 B): wb + full-size q/k/vT  -> 1 gemm + 1 attn
//   chunk path (ws >= 22,413,312 B): wb + 4-batch q/k/vT    -> 4x(gemm+attn)
extern "C" void kernel_launch(void* const* d_in, const int* in_sizes, int n_in,
                              void* d_out, int out_size, void* d_ws, size_t ws_size,
                              hipStream_t stream) {
    const float* x     = (const float*)d_in[0];   // (16,1024,768)
    const float* w     = (const float*)d_in[1];   // (2304,768)
    const float* bqkv  = (const float*)d_in[2];   // (2304,)
    const float* dvec  = (const float*)d_in[3];   // (1024,)
    const float* bbias = (const float*)d_in[4];   // (1024,1024)
    float* out = (float*)d_out;

    char* ws = (char*)d_ws;
    unsigned short* wb = (unsigned short*)ws;                        // 2304*768 bf16
    unsigned short* xb = (unsigned short*)((char*)d_out + 25165824); // 16*1024*768 bf16

    cvt_kernel<<<6144, 256, 0, stream>>>(x, xb, 1572864);            // all x -> bf16
    cvt_kernel<<<864, 256, 0, stream>>>(w, wb, 221184);              // w -> bf16

    const size_t NEED_FULL = 3538944ull + 3ull * 25165824ull;        // 79,036,416
    if (ws_size >= NEED_FULL) {
        unsigned short* qb = (unsigned short*)(ws + 3538944);        // 16*12*1024*64
        unsigned short* kb = qb + 12582912;
        unsigned short* vb = kb + 12582912;                          // V^T (bh,64,1024)
        qkv_gemm<<<dim3(18, 128), 256, 0, stream>>>(xb, wb, bqkv, qb, kb, vb);
        attn_kernel<<<1536, 512, 0, stream>>>(qb, kb, vb, bbias, dvec, out, 24);
    } else {
        unsigned short* qb = (unsigned short*)(ws + 3538944);        // 4*12*1024*64
        unsigned short* kb = qb + 3145728;
        unsigned short* vb = kb + 3145728;                           // V^T (bh,64,1024)
        for (int c = 0; c < 4; ++c) {
            const unsigned short* xc = xb + (size_t)c * 3145728;     // 4 batches
            qkv_gemm<<<dim3(18, 32), 256, 0, stream>>>(xc, wb, bqkv, qb, kb, vb);
            attn_kernel<<<384, 512, 0, stream>>>(
                qb, kb, vb, bbias, dvec, out + (size_t)c * 3145728, 6);
        }
    }
}

// Round 5
// 317.278 us; speedup vs baseline: 1.4761x; 1.0512x over previous
//
#include <hip/hip_runtime.h>
#include <cstdint>
#include <cstddef>

// ---------------- common ----------------
typedef __attribute__((ext_vector_type(8))) short short8;   // 8 x bf16 (4 VGPR)
typedef __attribute__((ext_vector_type(4))) short short4_;  // 4 x bf16 (2 VGPR)
typedef __attribute__((ext_vector_type(4))) float f32x4;    // MFMA C/D
typedef __attribute__((ext_vector_type(2))) unsigned int uint2_;

__device__ inline unsigned short bf16rne(float f) {
    uint32_t u = __builtin_bit_cast(uint32_t, f);
    u += 0x7fffu + ((u >> 16) & 1u);
    return (unsigned short)(u >> 16);
}

// async global->LDS, 16 B per lane. LDS dest = wave-uniform base + lane*16.
// CONTRACT (m104/m108): data lands at base + laneid*16 regardless of per-lane
// pointer; layout must be hole-free in lane order, ALL 64 lanes active.
#define GLDS(g, l)                                                              \
    __builtin_amdgcn_global_load_lds(                                           \
        (const __attribute__((address_space(1))) void*)(g),                     \
        (__attribute__((address_space(3))) void*)(l), 16, 0, 0)

// ---------------- fp32 -> bf16 convert ----------------
__global__ void cvt_kernel(const float* __restrict__ src,
                           unsigned short* __restrict__ dst, int n8) {
    int i = blockIdx.x * blockDim.x + threadIdx.x;
    if (i >= n8) return;
    const float4* s = (const float4*)src + (size_t)i * 2;
    float4 a = s[0], b = s[1];
    uint32_t w0 = bf16rne(a.x) | ((uint32_t)bf16rne(a.y) << 16);
    uint32_t w1 = bf16rne(a.z) | ((uint32_t)bf16rne(a.w) << 16);
    uint32_t w2 = bf16rne(b.x) | ((uint32_t)bf16rne(b.y) << 16);
    uint32_t w3 = bf16rne(b.z) | ((uint32_t)bf16rne(b.w) << 16);
    uint4 o; o.x = w0; o.y = w1; o.z = w2; o.w = w3;
    ((uint4*)dst)[i] = o;
}

// ---------------- QKV projection GEMM ----------------
// R10 rewrite (theory: fragment reads at row-stride 128 B = bank period ->
// all 16 m16-lanes of a quad on the same 4 banks = 2x LDS cycles; at 128^2
// tile LDS is exactly MFMA-balanced (125 of 128 B/cyc) so conflicts cap
// MfmaUtil directly):
//   - BK=32 double-buffered 2-phase: stage kt+1 before computing kt, ONE
//     barrier/iter (drains prefetch that had the whole compute phase to land).
//     Same 33 KB LDS footprint -> same 4 blocks/CU.
//   - XOR chunk-swizzle: slot (row, c') holds global chunk c = c'^(row&3);
//     pre-swizzled GLOBAL source (GLDS dest stays linear, m173 pattern),
//     ds_read at chunk quad^(m16&3). Enumeration: 8 lanes per 4-bank group =
//     wave64-b128 minimum -> conflict-free.
//   - XCD remap: each XCD owns a contiguous m-slab swept n-fastest -> X
//     panels fetched by exactly 1 XCD L2; W stays L2-resident per XCD.
//   - Q output pre-scaled by 0.125 (exponent shift, bit-exact) so attn's
//     softmax drops its scale VALU entirely.
// C[i][n] = sum_k X[i][k]*W[n][k] + b[n]; M = 16384(full)/4096(chunk), K=768,
// N=2304. q,k stored bf16 (b*12+h,1024,64) row-major (q pre-scaled 0.125);
// v stored TRANSPOSED (b*12+h,64,1024).
__global__ __launch_bounds__(256) void qkv_gemm(
    const unsigned short* __restrict__ X, const unsigned short* __restrict__ W,
    const float* __restrict__ bqkv,
    unsigned short* __restrict__ qo, unsigned short* __restrict__ ko,
    unsigned short* __restrict__ vo)
{
    __shared__ unsigned short smem[16896];   // As[2][4096] Bs[2][4096] | epi Cs 128x132
    unsigned short* As = smem;
    unsigned short* Bs = smem + 8192;

    const int tid  = threadIdx.x;
    // XCD-aware remap: f = dispatch-linear id, xcd = f&7 (grid % 8 == 0),
    // work = xcd*per + f>>3 -> contiguous per XCD; decode n-fastest.
    const int f    = blockIdx.x + gridDim.x * blockIdx.y;
    const int per  = (gridDim.x * gridDim.y) >> 3;
    const int wk   = (f & 7) * per + (f >> 3);
    const int m0   = (wk / 18) * 128;
    const int n0   = (wk % 18) * 128;
    const int wid  = tid >> 6;
    const int lane = tid & 63;
    const int m16  = lane & 15;
    const int quad = lane >> 4;
    const int wm   = wid >> 1, wn = wid & 1;

    f32x4 acc[4][4];
    #pragma unroll
    for (int i = 0; i < 4; i++)
        #pragma unroll
        for (int j = 0; j < 4; j++) acc[i][j] = (f32x4){0.f, 0.f, 0.f, 0.f};

    // stage one BK=32 tile into buffer buf (pre-swizzled global source)
    auto stage = [&](int buf, int k0) {
        #pragma unroll
        for (int rd = 0; rd < 2; ++rd) {
            int id = rd * 256 + tid;
            int row = id >> 2;
            int cs = (id & 3) ^ (row & 3);
            GLDS(X + (size_t)(m0 + row) * 768 + k0 + cs * 8, &As[buf * 4096 + id * 8]);
        }
        #pragma unroll
        for (int rd = 0; rd < 2; ++rd) {
            int id = rd * 256 + tid;
            int row = id >> 2;
            int cs = (id & 3) ^ (row & 3);
            GLDS(W + (size_t)(n0 + row) * 768 + k0 + cs * 8, &Bs[buf * 4096 + id * 8]);
        }
    };

    stage(0, 0);
    __syncthreads();

    const int csw = (quad ^ (m16 & 3)) * 8;   // swizzled chunk offset for frags
    for (int kt = 0; kt < 24; ++kt) {
        const int cur = kt & 1;
        if (kt < 23) stage(cur ^ 1, (kt + 1) * 32);

        short8 a[4], b[4];
        #pragma unroll
        for (int mb = 0; mb < 4; mb++)
            a[mb] = *(const short8*)&As[cur * 4096 + (wm * 64 + mb * 16 + m16) * 32 + csw];
        #pragma unroll
        for (int nb = 0; nb < 4; nb++)
            b[nb] = *(const short8*)&Bs[cur * 4096 + (wn * 64 + nb * 16 + m16) * 32 + csw];
        __builtin_amdgcn_s_setprio(1);
        #pragma unroll
        for (int mb = 0; mb < 4; mb++)
            #pragma unroll
            for (int nb = 0; nb < 4; nb++)
                acc[mb][nb] = __builtin_amdgcn_mfma_f32_16x16x32_bf16(
                    a[mb], b[nb], acc[mb][nb], 0, 0, 0);
        __builtin_amdgcn_s_setprio(0);
        __syncthreads();
    }

    float bias_n[4];
    #pragma unroll
    for (int nb = 0; nb < 4; nb++) bias_n[nb] = bqkv[n0 + wn * 64 + nb * 16 + m16];

    const int which = n0 / 768;
    const int hbase = (n0 % 768) / 64;
    const int bI  = m0 >> 10;      // batch index
    const int ns0 = m0 & 1023;

    if (which == 2) {
        // V: write transposed directly from acc (C-layout lane holds 4 consecutive
        // pos = quad*4+r for a fixed d-column) -> b64 stores into (bh,64,1024).
        #pragma unroll
        for (int mb = 0; mb < 4; ++mb)
            #pragma unroll
            for (int nb = 0; nb < 4; ++nb) {
                int n  = wn * 64 + nb * 16 + m16;
                int hh = hbase + (n >> 6);
                int d  = n & 63;
                int pos = ns0 + wm * 64 + mb * 16 + quad * 4;
                short4_ v4;
                #pragma unroll
                for (int r = 0; r < 4; ++r)
                    v4[r] = (short)bf16rne(acc[mb][nb][r] + bias_n[nb]);
                *(short4_*)(vo + ((size_t)(bI * 12 + hh) * 64 + d) * 1024 + pos) = v4;
            }
        return;
    }

    // Q/K: bias (+0.125 scale for Q: exponent shift, bit-exact), bf16, repack
    // via LDS (stride 132), row-major (bh,1024,64) stores
    const float qscale = (which == 0) ? 0.125f : 1.0f;
    #pragma unroll
    for (int mb = 0; mb < 4; mb++)
        #pragma unroll
        for (int nb = 0; nb < 4; nb++)
            #pragma unroll
            for (int r = 0; r < 4; r++) {
                float v = (acc[mb][nb][r] + bias_n[nb]) * qscale;
                smem[(wm * 64 + mb * 16 + quad * 4 + r) * 132 + wn * 64 + nb * 16 + m16] =
                    bf16rne(v);
            }
    __syncthreads();

    unsigned short* outp = (which == 0) ? qo : ko;
    #pragma unroll
    for (int rd = 0; rd < 8; ++rd) {
        int id = rd * 256 + tid;
        int row = id >> 4, c = id & 15;
        short4_ lo = *(const short4_*)&smem[row * 132 + c * 8];
        short4_ hi = *(const short4_*)&smem[row * 132 + c * 8 + 4];
        short8 v8 = __builtin_shufflevector(lo, hi, 0, 1, 2, 3, 4, 5, 6, 7);
        int h  = hbase + (c >> 3);
        int dc = (c & 7) * 8;
        unsigned short* dst =
            outp + ((size_t)(bI * 12 + h) * 1024 + ns0 + row) * 64 + dc;
        *(short8*)dst = v8;
    }
}

// ---------------- flash attention (S^T formulation, double-buffered) ----------
// R10 deltas (attn dispatch @148 µs, VALUBusy 40 / MfmaUtil 21.5 / Occ 60):
// VALU is the largest consumer (~200 cyc/iter vs ~100 MFMA). Cuts:
//   - Q arrives pre-scaled by 0.125 -> sc C-init = bias directly; the x8 init
//     and x0.125 post-scale are GONE (-32 VALU/iter, bit-exact).
//   - exp(s-m) = exp2(fma(s, log2e, -m*log2e)): 1 fma + 1 exp vs sub+mul+exp
//     (-16 VALU/iter).
//   - T5 setprio(1) around both MFMA clusters (+4-7% measured on attn).
// Structure unchanged from R9: 512 threads, q-tile 128, 32 KB dbuf LDS,
// launch_bounds(512,4), T3 2-phase prefetch, T13 defer-rescale THR=0.
//   Ks slot = pos*8 + (db ^ (pos&7)) -> b128 reads hit 8 dwords/bank (min)
//   Vs slot = pb*64 + d              -> b64  reads hit 4 dwords/bank (min)
__global__ __launch_bounds__(512, 4) void attn_kernel(
    const unsigned short* __restrict__ Q, const unsigned short* __restrict__ K,
    const unsigned short* __restrict__ Vt, const float* __restrict__ bias,
    const float* __restrict__ dvec, float* __restrict__ out, int nbh8)
{
    __shared__ unsigned short Ks[2][4096];   // 2 x 512 slots * 8 elems = 16 KB
    __shared__ unsigned short Vs[2][4096];   // 2 x 512 slots * 8 elems = 16 KB

    const int tid  = threadIdx.x;
    const int wid  = tid >> 6;               // 0..7
    const int lane = tid & 63;
    const int m16  = lane & 15;
    const int quad = lane >> 4;

    const int f    = blockIdx.x;
    const int xcd  = f & 7;
    const int r_   = f >> 3;
    const int qt   = r_ & 7;                 // 8 q-tiles of 128 rows
    const int bhl  = r_ >> 3;
    const int bh   = xcd * nbh8 + bhl;
    const int b = bh / 12, h = bh % 12;
    const int q0 = qt * 128;
    const int qrow = q0 + wid * 16 + m16;    // this lane's q row (column of S^T)

    const unsigned short* Qb = Q  + (size_t)bh * 65536;
    const unsigned short* Kb = K  + (size_t)bh * 65536;
    const unsigned short* Vb = Vt + (size_t)bh * 65536;
    const float* brow = bias + (size_t)qrow * 1024 + quad * 4;

    // kv-invariant staging source offsets (hole-free, all 512 lanes active;
    // one GLDS per thread per buffer: 512 slots x 8 elems = 64x64 tile)
    int k_src, v_src;
    {
        int pos = tid >> 3, dbs = tid & 7;
        int db = dbs ^ (pos & 7);             // un-swizzle: slot id holds this db
        k_src = pos * 64 + db * 8;
        int pb = tid >> 6, d = tid & 63;
        v_src = d * 1024 + pb * 8;
    }

    // Q fragments: B-operand of 16x16x32 (lane n=m16 holds dims quad*8..+8)
    short8 qf0 = *(const short8*)(Qb + (size_t)qrow * 64 + quad * 8);
    short8 qf1 = *(const short8*)(Qb + (size_t)qrow * 64 + 32 + quad * 8);

    f32x4 acc[4];
    #pragma unroll
    for (int nb = 0; nb < 4; nb++) acc[nb] = (f32x4){0.f, 0.f, 0.f, 0.f};
    float m_i = -3.0e38f, l_i = 0.f;
    const float L2E = 1.4426950408889634f;

    // prologue: stage tile 0 + preload bias tile 0
    GLDS(Kb + k_src, &Ks[0][tid * 8]);
    GLDS(Vb + v_src, &Vs[0][tid * 8]);
    float4 bv[4];
    #pragma unroll
    for (int cb = 0; cb < 4; ++cb) bv[cb] = *(const float4*)(brow + cb * 16);
    __syncthreads();

    for (int kv = 0; kv < 16; ++kv) {
        const int cur = kv & 1;
        const int k0n = (kv + 1) * 64;

        // S^T C-init = bias (Q pre-scaled by 0.125 -> no scale ops needed).
        // Consumes bv; freed for the next-iter prefetch below.
        f32x4 sc[4];
        #pragma unroll
        for (int cb = 0; cb < 4; ++cb) {
            sc[cb][0] = bv[cb].x;
            sc[cb][1] = bv[cb].y;
            sc[cb][2] = bv[cb].z;
            sc[cb][3] = bv[cb].w;
        }

        // prefetch tile kv+1 (lands during this iter's compute; barrier drains)
        if (kv < 15) {
            GLDS(Kb + (size_t)k0n * 64 + k_src, &Ks[cur ^ 1][tid * 8]);
            GLDS(Vb + (size_t)k0n + v_src, &Vs[cur ^ 1][tid * 8]);
            #pragma unroll
            for (int cb = 0; cb < 4; ++cb)
                bv[cb] = *(const float4*)(brow + k0n + cb * 16);
        }

        // S^T = bias + K·Q'^T : sc[cb] rows = pos cb*16+quad*4+r, col = qrow
        __builtin_amdgcn_s_setprio(1);
        #pragma unroll
        for (int ks = 0; ks < 2; ++ks) {
            #pragma unroll
            for (int cb = 0; cb < 4; ++cb) {
                int pos = cb * 16 + m16;
                int slot = pos * 8 + ((ks * 4 + quad) ^ (m16 & 7));
                short8 a = *(const short8*)&Ks[cur][slot * 8];
                sc[cb] = __builtin_amdgcn_mfma_f32_16x16x32_bf16(
                    a, (ks == 0) ? qf0 : qf1, sc[cb], 0, 0, 0);
            }
        }
        __builtin_amdgcn_s_setprio(0);

        // running max (sc already in final domain)
        float mx = -3.0e38f;
        #pragma unroll
        for (int cb = 0; cb < 4; ++cb)
            mx = fmaxf(mx, fmaxf(fmaxf(sc[cb][0], sc[cb][1]), fmaxf(sc[cb][2], sc[cb][3])));
        mx = fmaxf(mx, __shfl_xor(mx, 16, 64));
        mx = fmaxf(mx, __shfl_xor(mx, 32, 64));

        // T13 defer-rescale (THR=0: exact — skipped only when per-row max
        // didn't grow, in which case the rescale would be exp(0)=1 anyway)
        if (!__all(mx <= m_i)) {
            float mnew = fmaxf(m_i, mx);
            float al = __builtin_amdgcn_exp2f((m_i - mnew) * L2E);
            m_i = mnew;
            l_i *= al;
            #pragma unroll
            for (int nb = 0; nb < 4; nb++) {
                acc[nb][0] *= al; acc[nb][1] *= al;
                acc[nb][2] *= al; acc[nb][3] *= al;
            }
        }
        const float nmL = -m_i * L2E;

        // exp2(fma) + row-sum + pack P^T via v_perm_b32 truncation
        float rs = 0.f;
        short4_ pf[4];
        #pragma unroll
        for (int cb = 0; cb < 4; ++cb) {
            float p0 = __builtin_amdgcn_exp2f(__builtin_fmaf(sc[cb][0], L2E, nmL));
            float p1 = __builtin_amdgcn_exp2f(__builtin_fmaf(sc[cb][1], L2E, nmL));
            float p2 = __builtin_amdgcn_exp2f(__builtin_fmaf(sc[cb][2], L2E, nmL));
            float p3 = __builtin_amdgcn_exp2f(__builtin_fmaf(sc[cb][3], L2E, nmL));
            rs += (p0 + p1) + (p2 + p3);
            uint2_ pd;
            pd[0] = __builtin_amdgcn_perm(__builtin_bit_cast(uint32_t, p1),
                                          __builtin_bit_cast(uint32_t, p0), 0x07060302u);
            pd[1] = __builtin_amdgcn_perm(__builtin_bit_cast(uint32_t, p3),
                                          __builtin_bit_cast(uint32_t, p2), 0x07060302u);
            pf[cb] = __builtin_bit_cast(short4_, pd);
        }
        rs += __shfl_xor(rs, 16, 64);
        rs += __shfl_xor(rs, 32, 64);
        l_i += rs;

        // O^T += V^T · P^T  (A = V^T frag from LDS, B = P^T in registers)
        __builtin_amdgcn_s_setprio(1);
        #pragma unroll
        for (int ks = 0; ks < 4; ++ks) {
            #pragma unroll
            for (int nb = 0; nb < 4; ++nb) {
                int slot = (ks * 2 + (quad >> 1)) * 64 + nb * 16 + m16;
                short4_ av = *(const short4_*)&Vs[cur][slot * 8 + (quad & 1) * 4];
                acc[nb] = __builtin_amdgcn_mfma_f32_16x16x16bf16_1k(av, pf[ks], acc[nb], 0, 0, 0);
            }
        }
        __builtin_amdgcn_s_setprio(0);

        // one barrier per iter: waits this iter's LDS reads AND drains the
        // prefetch (issued a full compute phase ago -> cheap)
        __syncthreads();
    }

    // epilogue: out = d[qrow]/l * O ; O^T C-layout: lane holds d = nb*16+quad*4+r
    float scl = dvec[qrow] / l_i;
    #pragma unroll
    for (int nb = 0; nb < 4; ++nb) {
        float4 o;
        o.x = acc[nb][0] * scl; o.y = acc[nb][1] * scl;
        o.z = acc[nb][2] * scl; o.w = acc[nb][3] * scl;
        *(float4*)(out + ((size_t)b * 1024 + qrow) * 768 + h * 64 + nb * 16 + quad * 4) = o;
    }
}

// ---------------- launch ----------------
// xb (bf16 x, 25165824 B) lives in the upper half of d_out; every gemm that
// reads an xb region precedes (stream order) any attn write to that region.
// Workspace is layout-adaptive on ws_size (constant across calls => the same
// work every call):
//   full path  (ws >= 79,036,416 B): wb + full-size q/k/vT  -> 1 gemm + 1 attn
//   chunk path (ws >= 22,413,312 B): wb + 4-batch q/k/vT    -> 4x(gemm+attn)
extern "C" void kernel_launch(void* const* d_in, const int* in_sizes, int n_in,
                              void* d_out, int out_size, void* d_ws, size_t ws_size,
                              hipStream_t stream) {
    const float* x     = (const float*)d_in[0];   // (16,1024,768)
    const float* w     = (const float*)d_in[1];   // (2304,768)
    const float* bqkv  = (const float*)d_in[2];   // (2304,)
    const float* dvec  = (const float*)d_in[3];   // (1024,)
    const float* bbias = (const float*)d_in[4];   // (1024,1024)
    float* out = (float*)d_out;

    char* ws = (char*)d_ws;
    unsigned short* wb = (unsigned short*)ws;                        // 2304*768 bf16
    unsigned short* xb = (unsigned short*)((char*)d_out + 25165824); // 16*1024*768 bf16

    cvt_kernel<<<6144, 256, 0, stream>>>(x, xb, 1572864);            // all x -> bf16
    cvt_kernel<<<864, 256, 0, stream>>>(w, wb, 221184);              // w -> bf16

    const size_t NEED_FULL = 3538944ull + 3ull * 25165824ull;        // 79,036,416
    if (ws_size >= NEED_FULL) {
        unsigned short* qb = (unsigned short*)(ws + 3538944);        // 16*12*1024*64
        unsigned short* kb = qb + 12582912;
        unsigned short* vb = kb + 12582912;                          // V^T (bh,64,1024)
        qkv_gemm<<<dim3(18, 128), 256, 0, stream>>>(xb, wb, bqkv, qb, kb, vb);
        attn_kernel<<<1536, 512, 0, stream>>>(qb, kb, vb, bbias, dvec, out, 24);
    } else {
        unsigned short* qb = (unsigned short*)(ws + 3538944);        // 4*12*1024*64
        unsigned short* kb = qb + 3145728;
        unsigned short* vb = kb + 3145728;                           // V^T (bh,64,1024)
        for (int c = 0; c < 4; ++c) {
            const unsigned short* xc = xb + (size_t)c * 3145728;     // 4 batches
            qkv_gemm<<<dim3(18, 32), 256, 0, stream>>>(xc, wb, bqkv, qb, kb, vb);
            attn_kernel<<<384, 512, 0, stream>>>(
                qb, kb, vb, bbias, dvec, out + (size_t)c * 3145728, 6);
        }
    }
}

// Round 6
// 314.725 us; speedup vs baseline: 1.4881x; 1.0081x over previous
//
#include <hip/hip_runtime.h>
#include <cstdint>
#include <cstddef>

// ---------------- common ----------------
typedef __attribute__((ext_vector_type(8))) short short8;   // 8 x bf16 (4 VGPR)
typedef __attribute__((ext_vector_type(4))) short short4_;  // 4 x bf16 (2 VGPR)
typedef __attribute__((ext_vector_type(4))) float f32x4;    // MFMA C/D
typedef __attribute__((ext_vector_type(2))) unsigned int uint2_;

__device__ inline unsigned short bf16rne(float f) {
    uint32_t u = __builtin_bit_cast(uint32_t, f);
    u += 0x7fffu + ((u >> 16) & 1u);
    return (unsigned short)(u >> 16);
}

// async global->LDS, 16 B per lane. LDS dest = wave-uniform base + lane*16.
// CONTRACT (m104/m108): data lands at base + laneid*16 regardless of per-lane
// pointer; layout must be hole-free in lane order, ALL 64 lanes active.
#define GLDS(g, l)                                                              \
    __builtin_amdgcn_global_load_lds(                                           \
        (const __attribute__((address_space(1))) void*)(g),                     \
        (__attribute__((address_space(3))) void*)(l), 16, 0, 0)

// ---------------- fp32 -> bf16 convert ----------------
__global__ void cvt_kernel(const float* __restrict__ src,
                           unsigned short* __restrict__ dst, int n8) {
    int i = blockIdx.x * blockDim.x + threadIdx.x;
    if (i >= n8) return;
    const float4* s = (const float4*)src + (size_t)i * 2;
    float4 a = s[0], b = s[1];
    uint32_t w0 = bf16rne(a.x) | ((uint32_t)bf16rne(a.y) << 16);
    uint32_t w1 = bf16rne(a.z) | ((uint32_t)bf16rne(a.w) << 16);
    uint32_t w2 = bf16rne(b.x) | ((uint32_t)bf16rne(b.y) << 16);
    uint32_t w3 = bf16rne(b.z) | ((uint32_t)bf16rne(b.w) << 16);
    uint4 o; o.x = w0; o.y = w1; o.z = w2; o.w = w3;
    ((uint4*)dst)[i] = o;
}

// ---------------- QKV projection GEMM (R11: 256x256, 8-wave, counted vmcnt) --
// Theory: old 2-phase 128^2 gemm ~145 µs (~400 TF) = the m233 2-phase ceiling
// (stage+vmcnt(0)+barrier per 16 MFMA). This kernel: T3+T4 deep pipeline:
//   - 256x256 tile, BK=64, 512 thr / 8 waves (2m x 4n), LDS 128 KB (2 bufs x
//     (A 32K + B 32K)), 1 block/CU — m201 geometry, 64 MFMA per barrier-pair.
//   - counted vmcnt: prologue stages 2 tiles (16 GLDS/wave in flight); loop
//     waits vmcnt(8) (= oldest tile landed, next tile still flying), raw
//     s_barrier, 24 ds_read_b128 + 64 MFMA (setprio-wrapped), s_barrier,
//     restage t+2 into the buffer just consumed. vmcnt(0) only at t=11.
//   - XOR chunk swizzle BOTH-sides (rule #21): GLDS source chunk = c^(row&7)
//     (LDS dest linear), ds_read chunk = (ks*4+quad)^(row&7) -> 8 dwords/bank
//     (b128 floor, conflict-free).
//   - XCD slab decode: grid%8==0; each XCD owns contiguous m-slab (X panel
//     3 MB < 4 MB L2), n-fastest sweep.
// Outputs: q stored TRANSPOSED d-major (b*12+h, 64, 1024), pre-scaled 0.125
//   (direct b64 scatter from acc, no repack; attn loads Q frags scalar, 1x).
// k stored row-major (b*12+h, 1024, 64) via 2-pass LDS repack.
// v stored TRANSPOSED (b*12+h, 64, 1024) direct b64 scatter.
__global__ __launch_bounds__(512, 2) void qkv_gemm(
    const unsigned short* __restrict__ X, const unsigned short* __restrict__ W,
    const float* __restrict__ bqkv,
    unsigned short* __restrict__ qo, unsigned short* __restrict__ ko,
    unsigned short* __restrict__ vo)
{
    __shared__ unsigned short smem[65536];   // 128 KB: As[2][16384] | Bs[2][16384]
    unsigned short* As = smem;
    unsigned short* Bs = smem + 32768;

    const int tid  = threadIdx.x;
    const int f    = blockIdx.x;
    const int per  = gridDim.x >> 3;          // grid % 8 == 0
    const int wk   = (f & 7) * per + (f >> 3);
    const int m0   = (wk / 9) * 256;
    const int n0   = (wk % 9) * 256;
    const int wid  = tid >> 6;
    const int lane = tid & 63;
    const int m16  = lane & 15;
    const int quad = lane >> 4;
    const int wm   = wid >> 2;                // 0..1 : 128 rows each
    const int wn   = wid & 3;                 // 0..3 : 64 cols each (= one head)

    f32x4 acc[8][4];
    #pragma unroll
    for (int i = 0; i < 8; i++)
        #pragma unroll
        for (int j = 0; j < 4; j++) acc[i][j] = (f32x4){0.f, 0.f, 0.f, 0.f};

    // stage one BK=64 tile pair into buffer buf (pre-swizzled global source)
    auto stage = [&](int buf, int k0) {
        #pragma unroll
        for (int rd = 0; rd < 4; ++rd) {
            int id = rd * 512 + tid;              // 0..2047 : 256 rows x 8 chunks
            int row = id >> 3;
            int cs = (id & 7) ^ (row & 7);
            GLDS(X + (size_t)(m0 + row) * 768 + k0 + cs * 8,
                 &As[buf * 16384 + id * 8]);
        }
        #pragma unroll
        for (int rd = 0; rd < 4; ++rd) {
            int id = rd * 512 + tid;
            int row = id >> 3;
            int cs = (id & 7) ^ (row & 7);
            GLDS(W + (size_t)(n0 + row) * 768 + k0 + cs * 8,
                 &Bs[buf * 16384 + id * 8]);
        }
    };

    stage(0, 0);
    stage(1, 64);

    const int arow0 = wm * 128 + m16;         // + mb*16
    const int brow0 = wn * 64 + m16;          // + nb*16
    const int swz   = m16 & 7;                // row&7 for all frag rows

    for (int t = 0; t < 12; ++t) {
        const int cur = t & 1;
        if (t == 11) asm volatile("s_waitcnt vmcnt(0)" ::: "memory");
        else         asm volatile("s_waitcnt vmcnt(8)" ::: "memory");
        __builtin_amdgcn_s_barrier();

        __builtin_amdgcn_s_setprio(1);
        #pragma unroll
        for (int ks = 0; ks < 2; ++ks) {
            const int ch = ((ks * 4 + quad) ^ swz) * 8;
            short8 b[4];
            #pragma unroll
            for (int nb = 0; nb < 4; nb++)
                b[nb] = *(const short8*)&Bs[cur * 16384 + (brow0 + nb * 16) * 64 + ch];
            #pragma unroll
            for (int mb = 0; mb < 8; mb++) {
                short8 a = *(const short8*)&As[cur * 16384 + (arow0 + mb * 16) * 64 + ch];
                #pragma unroll
                for (int nb = 0; nb < 4; nb++)
                    acc[mb][nb] = __builtin_amdgcn_mfma_f32_16x16x32_bf16(
                        a, b[nb], acc[mb][nb], 0, 0, 0);
            }
        }
        __builtin_amdgcn_s_setprio(0);

        __builtin_amdgcn_s_barrier();          // all waves done reading buf[cur]
        asm volatile("" ::: "memory");
        if (t < 10) stage(cur, (t + 2) * 64);  // overwrite consumed buffer
    }

    float bias_n[4];
    #pragma unroll
    for (int nb = 0; nb < 4; nb++) bias_n[nb] = bqkv[n0 + wn * 64 + nb * 16 + m16];

    const int which = n0 / 768;                // n-tiles align: 768 = 3*256
    const int hbase = (n0 % 768) >> 6;         // {0,4,8}
    const int bI  = m0 >> 10;                  // batch index (256 | 1024)
    const int ns0 = m0 & 1023;

    if (which != 1) {
        // Q (d-major, pre-scaled 0.125) and V (d-major): direct transposed
        // b64 stores from acc (lane holds 4 consecutive pos for fixed d).
        unsigned short* outp = (which == 0) ? qo : vo;
        const float scl = (which == 0) ? 0.125f : 1.0f;
        const int h = hbase + wn;
        #pragma unroll
        for (int mb = 0; mb < 8; ++mb)
            #pragma unroll
            for (int nb = 0; nb < 4; ++nb) {
                int d   = nb * 16 + m16;
                int pos = ns0 + wm * 128 + mb * 16 + quad * 4;
                short4_ v4;
                #pragma unroll
                for (int r = 0; r < 4; ++r)
                    v4[r] = (short)bf16rne((acc[mb][nb][r] + bias_n[nb]) * scl);
                *(short4_*)(outp + ((size_t)(bI * 12 + h) * 64 + d) * 1024 + pos) = v4;
            }
        return;
    }

    // K: row-major (bh,1024,64) via 2-pass LDS repack (256 rows x 128 cols/pass)
    #pragma unroll
    for (int pass = 0; pass < 2; ++pass) {
        __syncthreads();                       // region free / prior pass done
        if ((wn >> 1) == pass) {
            const int colb = (wn & 1) * 64;
            #pragma unroll
            for (int mb = 0; mb < 8; mb++)
                #pragma unroll
                for (int nb = 0; nb < 4; nb++)
                    #pragma unroll
                    for (int r = 0; r < 4; r++) {
                        float v = acc[mb][nb][r] + bias_n[nb];
                        smem[(wm * 128 + mb * 16 + quad * 4 + r) * 132 +
                             colb + nb * 16 + m16] = bf16rne(v);
                    }
        }
        __syncthreads();
        #pragma unroll
        for (int rd = 0; rd < 8; ++rd) {
            int id = rd * 512 + tid;           // 256 rows x 16 chunks
            int row = id >> 4, c = id & 15;
            short4_ lo = *(const short4_*)&smem[row * 132 + c * 8];
            short4_ hi = *(const short4_*)&smem[row * 132 + c * 8 + 4];
            short8 v8 = __builtin_shufflevector(lo, hi, 0, 1, 2, 3, 4, 5, 6, 7);
            int h  = hbase + pass * 2 + (c >> 3);
            int dc = (c & 7) * 8;
            unsigned short* dst =
                ko + ((size_t)(bI * 12 + h) * 1024 + ns0 + row) * 64 + dc;
            *(short8*)dst = v8;
        }
    }
}

// ---------------- flash attention (S^T formulation, double-buffered) ----------
// Unchanged from R10 except: Q is now stored d-major (bh,64,1024) by the gemm,
// so the per-block Q fragment load is 16 scalar u16 loads (amortized over 16
// kv iters — negligible). Everything else identical: 512 threads, q-tile 128,
// 32 KB dbuf LDS, launch_bounds(512,4), T3 2-phase prefetch, bias C-init
// (Q pre-scaled 0.125), exp2-fma softmax, T13 defer-rescale THR=0, T5 setprio.
//   Ks slot = pos*8 + (db ^ (pos&7)) -> b128 reads hit 8 dwords/bank (min)
//   Vs slot = pb*64 + d              -> b64  reads hit 4 dwords/bank (min)
__global__ __launch_bounds__(512, 4) void attn_kernel(
    const unsigned short* __restrict__ Q, const unsigned short* __restrict__ K,
    const unsigned short* __restrict__ Vt, const float* __restrict__ bias,
    const float* __restrict__ dvec, float* __restrict__ out, int nbh8)
{
    __shared__ unsigned short Ks[2][4096];   // 2 x 512 slots * 8 elems = 16 KB
    __shared__ unsigned short Vs[2][4096];   // 2 x 512 slots * 8 elems = 16 KB

    const int tid  = threadIdx.x;
    const int wid  = tid >> 6;               // 0..7
    const int lane = tid & 63;
    const int m16  = lane & 15;
    const int quad = lane >> 4;

    const int f    = blockIdx.x;
    const int xcd  = f & 7;
    const int r_   = f >> 3;
    const int qt   = r_ & 7;                 // 8 q-tiles of 128 rows
    const int bhl  = r_ >> 3;
    const int bh   = xcd * nbh8 + bhl;
    const int b = bh / 12, h = bh % 12;
    const int q0 = qt * 128;
    const int qrow = q0 + wid * 16 + m16;    // this lane's q row (column of S^T)

    const unsigned short* Qb = Q  + (size_t)bh * 65536;
    const unsigned short* Kb = K  + (size_t)bh * 65536;
    const unsigned short* Vb = Vt + (size_t)bh * 65536;
    const float* brow = bias + (size_t)qrow * 1024 + quad * 4;

    // kv-invariant staging source offsets (hole-free, all 512 lanes active;
    // one GLDS per thread per buffer: 512 slots x 8 elems = 64x64 tile)
    int k_src, v_src;
    {
        int pos = tid >> 3, dbs = tid & 7;
        int db = dbs ^ (pos & 7);             // un-swizzle: slot id holds this db
        k_src = pos * 64 + db * 8;
        int pb = tid >> 6, d = tid & 63;
        v_src = d * 1024 + pb * 8;
    }

    // Q fragments from d-major Q: lane (m16,quad) needs dims quad*8..+8 (qf0)
    // and 32+quad*8..+8 (qf1) of row qrow -> 16 scalar loads, once per block.
    short8 qf0, qf1;
    #pragma unroll
    for (int j = 0; j < 8; ++j) {
        qf0[j] = (short)Qb[(size_t)(quad * 8 + j) * 1024 + qrow];
        qf1[j] = (short)Qb[(size_t)(32 + quad * 8 + j) * 1024 + qrow];
    }

    f32x4 acc[4];
    #pragma unroll
    for (int nb = 0; nb < 4; nb++) acc[nb] = (f32x4){0.f, 0.f, 0.f, 0.f};
    float m_i = -3.0e38f, l_i = 0.f;
    const float L2E = 1.4426950408889634f;

    // prologue: stage tile 0 + preload bias tile 0
    GLDS(Kb + k_src, &Ks[0][tid * 8]);
    GLDS(Vb + v_src, &Vs[0][tid * 8]);
    float4 bv[4];
    #pragma unroll
    for (int cb = 0; cb < 4; ++cb) bv[cb] = *(const float4*)(brow + cb * 16);
    __syncthreads();

    for (int kv = 0; kv < 16; ++kv) {
        const int cur = kv & 1;
        const int k0n = (kv + 1) * 64;

        // S^T C-init = bias (Q pre-scaled by 0.125 -> no scale ops needed).
        // Consumes bv; freed for the next-iter prefetch below.
        f32x4 sc[4];
        #pragma unroll
        for (int cb = 0; cb < 4; ++cb) {
            sc[cb][0] = bv[cb].x;
            sc[cb][1] = bv[cb].y;
            sc[cb][2] = bv[cb].z;
            sc[cb][3] = bv[cb].w;
        }

        // prefetch tile kv+1 (lands during this iter's compute; barrier drains)
        if (kv < 15) {
            GLDS(Kb + (size_t)k0n * 64 + k_src, &Ks[cur ^ 1][tid * 8]);
            GLDS(Vb + (size_t)k0n + v_src, &Vs[cur ^ 1][tid * 8]);
            #pragma unroll
            for (int cb = 0; cb < 4; ++cb)
                bv[cb] = *(const float4*)(brow + k0n + cb * 16);
        }

        // S^T = bias + K·Q'^T : sc[cb] rows = pos cb*16+quad*4+r, col = qrow
        __builtin_amdgcn_s_setprio(1);
        #pragma unroll
        for (int ks = 0; ks < 2; ++ks) {
            #pragma unroll
            for (int cb = 0; cb < 4; ++cb) {
                int pos = cb * 16 + m16;
                int slot = pos * 8 + ((ks * 4 + quad) ^ (m16 & 7));
                short8 a = *(const short8*)&Ks[cur][slot * 8];
                sc[cb] = __builtin_amdgcn_mfma_f32_16x16x32_bf16(
                    a, (ks == 0) ? qf0 : qf1, sc[cb], 0, 0, 0);
            }
        }
        __builtin_amdgcn_s_setprio(0);

        // running max (sc already in final domain)
        float mx = -3.0e38f;
        #pragma unroll
        for (int cb = 0; cb < 4; ++cb)
            mx = fmaxf(mx, fmaxf(fmaxf(sc[cb][0], sc[cb][1]), fmaxf(sc[cb][2], sc[cb][3])));
        mx = fmaxf(mx, __shfl_xor(mx, 16, 64));
        mx = fmaxf(mx, __shfl_xor(mx, 32, 64));

        // T13 defer-rescale (THR=0: exact — skipped only when per-row max
        // didn't grow, in which case the rescale would be exp(0)=1 anyway)
        if (!__all(mx <= m_i)) {
            float mnew = fmaxf(m_i, mx);
            float al = __builtin_amdgcn_exp2f((m_i - mnew) * L2E);
            m_i = mnew;
            l_i *= al;
            #pragma unroll
            for (int nb = 0; nb < 4; nb++) {
                acc[nb][0] *= al; acc[nb][1] *= al;
                acc[nb][2] *= al; acc[nb][3] *= al;
            }
        }
        const float nmL = -m_i * L2E;

        // exp2(fma) + row-sum + pack P^T via v_perm_b32 truncation
        float rs = 0.f;
        short4_ pf[4];
        #pragma unroll
        for (int cb = 0; cb < 4; ++cb) {
            float p0 = __builtin_amdgcn_exp2f(__builtin_fmaf(sc[cb][0], L2E, nmL));
            float p1 = __builtin_amdgcn_exp2f(__builtin_fmaf(sc[cb][1], L2E, nmL));
            float p2 = __builtin_amdgcn_exp2f(__builtin_fmaf(sc[cb][2], L2E, nmL));
            float p3 = __builtin_amdgcn_exp2f(__builtin_fmaf(sc[cb][3], L2E, nmL));
            rs += (p0 + p1) + (p2 + p3);
            uint2_ pd;
            pd[0] = __builtin_amdgcn_perm(__builtin_bit_cast(uint32_t, p1),
                                          __builtin_bit_cast(uint32_t, p0), 0x07060302u);
            pd[1] = __builtin_amdgcn_perm(__builtin_bit_cast(uint32_t, p3),
                                          __builtin_bit_cast(uint32_t, p2), 0x07060302u);
            pf[cb] = __builtin_bit_cast(short4_, pd);
        }
        rs += __shfl_xor(rs, 16, 64);
        rs += __shfl_xor(rs, 32, 64);
        l_i += rs;

        // O^T += V^T · P^T  (A = V^T frag from LDS, B = P^T in registers)
        __builtin_amdgcn_s_setprio(1);
        #pragma unroll
        for (int ks = 0; ks < 4; ++ks) {
            #pragma unroll
            for (int nb = 0; nb < 4; ++nb) {
                int slot = (ks * 2 + (quad >> 1)) * 64 + nb * 16 + m16;
                short4_ av = *(const short4_*)&Vs[cur][slot * 8 + (quad & 1) * 4];
                acc[nb] = __builtin_amdgcn_mfma_f32_16x16x16bf16_1k(av, pf[ks], acc[nb], 0, 0, 0);
            }
        }
        __builtin_amdgcn_s_setprio(0);

        // one barrier per iter: waits this iter's LDS reads AND drains the
        // prefetch (issued a full compute phase ago -> cheap)
        __syncthreads();
    }

    // epilogue: out = d[qrow]/l * O ; O^T C-layout: lane holds d = nb*16+quad*4+r
    float scl = dvec[qrow] / l_i;
    #pragma unroll
    for (int nb = 0; nb < 4; ++nb) {
        float4 o;
        o.x = acc[nb][0] * scl; o.y = acc[nb][1] * scl;
        o.z = acc[nb][2] * scl; o.w = acc[nb][3] * scl;
        *(float4*)(out + ((size_t)b * 1024 + qrow) * 768 + h * 64 + nb * 16 + quad * 4) = o;
    }
}

// ---------------- launch ----------------
// xb (bf16 x, 25165824 B) lives in the upper half of d_out; every gemm that
// reads an xb region precedes (stream order) any attn write to that region.
// Workspace is layout-adaptive on ws_size (constant across calls => the same
// work every call):
//   full path  (ws >= 79,036,416 B): wb + full-size q/k/vT  -> 1 gemm + 1 attn
//   chunk path (ws >= 22,413,312 B): wb + 4-batch q/k/vT    -> 4x(gemm+attn)
extern "C" void kernel_launch(void* const* d_in, const int* in_sizes, int n_in,
                              void* d_out, int out_size, void* d_ws, size_t ws_size,
                              hipStream_t stream) {
    const float* x     = (const float*)d_in[0];   // (16,1024,768)
    const float* w     = (const float*)d_in[1];   // (2304,768)
    const float* bqkv  = (const float*)d_in[2];   // (2304,)
    const float* dvec  = (const float*)d_in[3];   // (1024,)
    const float* bbias = (const float*)d_in[4];   // (1024,1024)
    float* out = (float*)d_out;

    char* ws = (char*)d_ws;
    unsigned short* wb = (unsigned short*)ws;                        // 2304*768 bf16
    unsigned short* xb = (unsigned short*)((char*)d_out + 25165824); // 16*1024*768 bf16

    cvt_kernel<<<6144, 256, 0, stream>>>(x, xb, 1572864);            // all x -> bf16
    cvt_kernel<<<864, 256, 0, stream>>>(w, wb, 221184);              // w -> bf16

    const size_t NEED_FULL = 3538944ull + 3ull * 25165824ull;        // 79,036,416
    if (ws_size >= NEED_FULL) {
        unsigned short* qb = (unsigned short*)(ws + 3538944);        // 16*12*1024*64
        unsigned short* kb = qb + 12582912;
        unsigned short* vb = kb + 12582912;                          // V^T (bh,64,1024)
        qkv_gemm<<<576, 512, 0, stream>>>(xb, wb, bqkv, qb, kb, vb); // 64x9 256^2 tiles
        attn_kernel<<<1536, 512, 0, stream>>>(qb, kb, vb, bbias, dvec, out, 24);
    } else {
        unsigned short* qb = (unsigned short*)(ws + 3538944);        // 4*12*1024*64
        unsigned short* kb = qb + 3145728;
        unsigned short* vb = kb + 3145728;                           // V^T (bh,64,1024)
        for (int c = 0; c < 4; ++c) {
            const unsigned short* xc = xb + (size_t)c * 3145728;     // 4 batches
            qkv_gemm<<<144, 512, 0, stream>>>(xc, wb, bqkv, qb, kb, vb); // 16x9
            attn_kernel<<<384, 512, 0, stream>>>(
                qb, kb, vb, bbias, dvec, out + (size_t)c * 3145728, 6);
        }
    }
}